// Round 8
// baseline (400.517 us; speedup 1.0000x reference)
//
#include <hip/hip_runtime.h>
#include <hip/hip_bf16.h>
#include <math.h>

// Shapes are fixed by the problem instance.
#define BDOCS   1024
#define CNODES  4096
#define INDIM   768
#define HID     512
#define NHEAD   4
#define HDIM    128
#define NEG_SLOPE 0.2f

#define KSPLIT  8
#define JPER    (CNODES / KSPLIT)   // 512
#define NCH     (JPER / 32)         // 16

typedef __attribute__((ext_vector_type(8))) short short8;   // 8 bf16 (4 VGPRs)
typedef __attribute__((ext_vector_type(4))) float f32x4;    // MFMA C/D

__device__ __forceinline__ float lrelu(float x) { return x > 0.f ? x : NEG_SLOPE * x; }

// float -> bf16 bits, round-to-nearest-even
__device__ __forceinline__ short f2bf(float f) {
    union { float f; unsigned u; } v; v.f = f;
    unsigned r = (v.u + 0x7fff + ((v.u >> 16) & 1)) >> 16;
    return (short)r;
}
__device__ __forceinline__ float bf2f(short s) {
    union { float f; unsigned u; } v; v.u = ((unsigned)(unsigned short)s) << 16;
    return v.f;
}
// pack 2 f32 -> dword of 2 bf16 (RNE)
__device__ __forceinline__ unsigned pk2(float a, float b) {
    union { float f; unsigned u; } x, y; x.f = a; y.f = b;
    unsigned lo = (x.u + 0x7fff + ((x.u >> 16) & 1)) >> 16;
    unsigned hi = (y.u + 0x7fff + ((y.u >> 16) & 1)) >> 16;
    return lo | (hi << 16);
}
// half-up round f32 -> bf16 (hot loop; w in [0,1])
__device__ __forceinline__ short hup(float f) {
    union { float f; unsigned u; } v; v.f = f;
    return (short)((v.u + 0x8000) >> 16);
}

// ---------------------------------------------------------------------------
// prep helpers as device functions (shared LDS tile passed in)
// ---------------------------------------------------------------------------
__device__ void frag_T_dev(const float* __restrict__ src, short* __restrict__ dst,
                           int N, int K, int jc, int nq, float (*tile)[132])
{
    const int t  = threadIdx.x;
    const int KC = K >> 5;
#pragma unroll
    for (int it = 0; it < 16; it++) {
        const int e = it * 256 + t;
        const int j = e >> 7, n = e & 127;
        tile[j][n] = src[(size_t)(jc * 32 + j) * N + nq * 128 + n];
    }
    __syncthreads();
#pragma unroll
    for (int s = 0; s < 2; s++) {
        const int item = s * 256 + t;
        const int nbl = item >> 6, lane = item & 63;
        const int nr = lane & 15, kq = lane >> 4;
        short8 v;
#pragma unroll
        for (int jr = 0; jr < 8; jr++)
            v[jr] = f2bf(tile[kq * 8 + jr][nbl * 16 + nr]);
        *(short8*)&dst[((size_t)((nq * 8 + nbl) * KC + jc) * 64 + lane) * 8] = v;
    }
}

__device__ void frag_A_dev(const float* __restrict__ src, short* __restrict__ dst,
                           int C, int rb, int cq, float (*tile)[132])
{
    const int t  = threadIdx.x;
    const int KC = C >> 5;
#pragma unroll
    for (int it = 0; it < 8; it++) {
        const int e = it * 256 + t;
        const int r = e >> 7, c = e & 127;
        tile[r][c] = src[(size_t)(rb * 16 + r) * C + cq * 128 + c];
    }
    __syncthreads();
    const int kcl = t >> 6, lane = t & 63;
    const int m = lane & 15, kq = lane >> 4;
    short8 v8;
#pragma unroll
    for (int j = 0; j < 8; j++) v8[j] = f2bf(tile[m][kcl * 32 + kq * 8 + j]);
    *(short8*)&dst[((size_t)(rb * KC + cq * 4 + kcl) * 64 + lane) * 8] = v8;
}

// ---------------------------------------------------------------------------
// prep_all: pack_adj (65536 blocks) + frag_T(Wd) + frag_T(W1) + frag_T(W2) +
// frag_A(doc_x) + frag_A(label_init), flattened into one grid.
// ---------------------------------------------------------------------------
#define PREP_BLOCKS (65536 + 96 + 96 + 64 + 384 + 1536)
__global__ __launch_bounds__(256)
void prep_all(const int* __restrict__ adj, unsigned long long* __restrict__ adjb64,
              const float* __restrict__ Wd, short* __restrict__ Wdf,
              const float* __restrict__ W1, short* __restrict__ W1f,
              const float* __restrict__ W2, short* __restrict__ W2f,
              const float* __restrict__ doc_x, short* __restrict__ dxf,
              const float* __restrict__ label_init, short* __restrict__ lif)
{
    __shared__ float tile[32][132];
    int b = blockIdx.x;
    if (b < 65536) {
        const int t    = threadIdx.x;
        const int gw   = b * 4 + (t >> 6);
        const int lane = t & 63;
        const int i  = gw >> 6;
        const int j0 = (gw & 63) * 64;
        const int a  = adj[(size_t)i * CNODES + j0 + lane];
        const unsigned long long msk = __ballot(a != 0);
        if (lane == 0) adjb64[(size_t)i * 64 + (j0 >> 6)] = msk;
        return;
    }
    b -= 65536;
    if (b < 96)  { frag_T_dev(Wd, Wdf, HID, INDIM, b % 24, b / 24, tile); return; }
    b -= 96;
    if (b < 96)  { frag_T_dev(W1, W1f, HID, INDIM, b % 24, b / 24, tile); return; }
    b -= 96;
    if (b < 64)  { frag_T_dev(W2, W2f, HID, HID, b % 16, b / 16, tile); return; }
    b -= 64;
    if (b < 384) { frag_A_dev(doc_x, dxf, INDIM, b % 64, b / 64, tile); return; }
    b -= 384;
    frag_A_dev(label_init, lif, INDIM, b % 256, b / 256, tile);
}

// ---------------------------------------------------------------------------
// gemm_hpre: hpre tile = A @ B^T. m-tile 16 -> grid (CNODES/16, NHEAD).
// Epilogue: (a) half-B-frags of bf16(hpre) -> hbTf, (b) asrc/adst row dots.
// ---------------------------------------------------------------------------
template <int KC>
__global__ __launch_bounds__(64)
void gemm_hpre(const short* __restrict__ Af, const short* __restrict__ Bf,
               const float* __restrict__ a_src, const float* __restrict__ a_dst,
               short* __restrict__ hbTf, float* __restrict__ asrc, float* __restrict__ adst)
{
    __shared__ __align__(16) short tileT[128][24];   // [col][localrow]
    const int lane = threadIdx.x;
    const int mb   = blockIdx.x;       // 0..255
    const int nq   = blockIdx.y;       // head
    const int i0   = mb * 16;

    f32x4 acc[8];
#pragma unroll
    for (int c = 0; c < 8; c++) acc[c] = (f32x4){0.f, 0.f, 0.f, 0.f};

    const short* ap = Af + (size_t)mb * KC * 512 + lane * 8;
    const short* bp = Bf + (size_t)(nq * 8) * KC * 512 + lane * 8;

#pragma unroll 2
    for (int kc = 0; kc < KC; kc++) {
        short8 a = *(const short8*)(ap + (size_t)kc * 512);
#pragma unroll
        for (int c = 0; c < 8; c++) {
            short8 bf = *(const short8*)(bp + ((size_t)c * KC + kc) * 512);
            acc[c] = __builtin_amdgcn_mfma_f32_16x16x32_bf16(a, bf, acc[c], 0, 0, 0);
        }
    }

    const int col = lane & 15, q4 = lane >> 4;

#pragma unroll
    for (int c = 0; c < 8; c++) {
        uint2 u;
        u.x = pk2(acc[c][0], acc[c][1]);
        u.y = pk2(acc[c][2], acc[c][3]);
        *(uint2*)&tileT[c * 16 + col][q4 * 4] = u;
    }
    __syncthreads();
    {
        const int jc = mb >> 1, khalf = mb & 1;
        const int nr = lane & 15, kq = lane >> 4;
        if ((kq >> 1) == khalf) {
#pragma unroll
            for (int nbl = 0; nbl < 8; nbl++) {
                short8 v = *(const short8*)&tileT[nbl * 16 + nr][(kq & 1) * 8];
                *(short8*)&hbTf[(((size_t)(nq * 8 + nbl) * (CNODES / 32) + jc) * 64 + lane) * 8] = v;
            }
        }
    }

    float ssrc[4] = {}, sdst[4] = {};
#pragma unroll
    for (int c = 0; c < 8; c++) {
        const float vs = a_src[nq * 128 + c * 16 + col];
        const float vd = a_dst[nq * 128 + c * 16 + col];
#pragma unroll
        for (int r = 0; r < 4; r++) {
            ssrc[r] += acc[c][r] * vs;
            sdst[r] += acc[c][r] * vd;
        }
    }
#pragma unroll
    for (int mask = 1; mask <= 8; mask <<= 1)
#pragma unroll
        for (int r = 0; r < 4; r++) {
            ssrc[r] += __shfl_xor(ssrc[r], mask);
            sdst[r] += __shfl_xor(sdst[r], mask);
        }
    if (col == 0) {
#pragma unroll
        for (int r = 0; r < 4; r++) {
            const int row = i0 + q4 * 4 + r;
            asrc[nq * CNODES + row] = ssrc[r];
            adst[nq * CNODES + row] = sdst[r];
        }
    }
}

// ---------------------------------------------------------------------------
// gemm_doc: doc_h tile = relu(A @ B^T + bias) -> bf16 A-frags (dhf).
// ---------------------------------------------------------------------------
template <int KC>
__global__ __launch_bounds__(64)
void gemm_doc(const short* __restrict__ Af, const short* __restrict__ Bf,
              const float* __restrict__ bias, short* __restrict__ dhf)
{
    __shared__ __align__(16) short tile[16][64];
    const int lane = threadIdx.x;
    const int mb = blockIdx.x;
    const int ng = blockIdx.y;

    f32x4 acc[4];
#pragma unroll
    for (int c = 0; c < 4; c++) acc[c] = (f32x4){0.f, 0.f, 0.f, 0.f};

    const short* ap = Af + (size_t)mb * KC * 512 + lane * 8;
    const short* bp = Bf + (size_t)(ng * 4) * KC * 512 + lane * 8;

#pragma unroll 2
    for (int kc = 0; kc < KC; kc++) {
        short8 a = *(const short8*)(ap + (size_t)kc * 512);
#pragma unroll
        for (int c = 0; c < 4; c++) {
            short8 bf = *(const short8*)(bp + ((size_t)c * KC + kc) * 512);
            acc[c] = __builtin_amdgcn_mfma_f32_16x16x32_bf16(a, bf, acc[c], 0, 0, 0);
        }
    }

    const int col = lane & 15, q4 = lane >> 4;
#pragma unroll
    for (int c = 0; c < 4; c++)
#pragma unroll
        for (int r = 0; r < 4; r++) {
            float v = fmaxf(acc[c][r] + bias[ng * 64 + c * 16 + col], 0.f);
            tile[q4 * 4 + r][c * 16 + col] = f2bf(v);
        }
    __syncthreads();
    const int m = lane & 15, kq = lane >> 4;
#pragma unroll
    for (int kcl = 0; kcl < 2; kcl++) {
        short8 v = *(const short8*)&tile[m][kcl * 32 + kq * 8];
        *(short8*)&dhf[(((size_t)mb * 16 + ng * 2 + kcl) * 64 + lane) * 8] = v;
    }
}

// ---------------------------------------------------------------------------
// gemm_frag: C[M][N] fp32 = A @ B^T from bf16 fragments (logits).
// ---------------------------------------------------------------------------
template <int KC>
__global__ __launch_bounds__(64)
void gemm_frag(const short* __restrict__ Af, const short* __restrict__ Bf,
               float* __restrict__ Cmat, int N)
{
    const int lane = threadIdx.x;
    const int mb0  = blockIdx.x * 2;
    const int nq   = blockIdx.y;

    f32x4 acc[2][8];
#pragma unroll
    for (int f = 0; f < 2; f++)
#pragma unroll
        for (int c = 0; c < 8; c++) acc[f][c] = (f32x4){0.f, 0.f, 0.f, 0.f};

    const short* ap0 = Af + (size_t)mb0 * KC * 512 + lane * 8;
    const short* ap1 = ap0 + (size_t)KC * 512;
    const short* bp  = Bf + (size_t)(nq * 8) * KC * 512 + lane * 8;

#pragma unroll 2
    for (int kc = 0; kc < KC; kc++) {
        short8 a0 = *(const short8*)(ap0 + (size_t)kc * 512);
        short8 a1 = *(const short8*)(ap1 + (size_t)kc * 512);
#pragma unroll
        for (int c = 0; c < 8; c++) {
            short8 bf = *(const short8*)(bp + ((size_t)c * KC + kc) * 512);
            acc[0][c] = __builtin_amdgcn_mfma_f32_16x16x32_bf16(a0, bf, acc[0][c], 0, 0, 0);
            acc[1][c] = __builtin_amdgcn_mfma_f32_16x16x32_bf16(a1, bf, acc[1][c], 0, 0, 0);
        }
    }

    const int col = lane & 15, q4 = lane >> 4;
#pragma unroll
    for (int f = 0; f < 2; f++)
#pragma unroll
        for (int c = 0; c < 8; c++)
#pragma unroll
            for (int r = 0; r < 4; r++) {
                const int row = (mb0 + f) * 16 + q4 * 4 + r;
                Cmat[(size_t)row * N + nq * 128 + c * 16 + col] = acc[f][c][r];
            }
}

// ---------------------------------------------------------------------------
// stats_exp: Mh[h] = max_j adst[h][j]; E1 = exp(adst-Mh); E2 = exp(0.2*(...)).
// ---------------------------------------------------------------------------
__global__ __launch_bounds__(1024)
void stats_exp(const float* __restrict__ adst, float* __restrict__ Mh,
               float* __restrict__ E1, float* __restrict__ E2)
{
    __shared__ float red[1024];
    __shared__ float s_mh;
    const int h = blockIdx.x, t = threadIdx.x;
    const float4 d4 = *(const float4*)(adst + (size_t)h * CNODES + t * 4);
    float m = fmaxf(fmaxf(d4.x, d4.y), fmaxf(d4.z, d4.w));
    red[t] = m; __syncthreads();
    for (int s = 512; s >= 1; s >>= 1) {
        if (t < s) red[t] = fmaxf(red[t], red[t + s]);
        __syncthreads();
    }
    if (t == 0) { s_mh = red[0]; Mh[h] = red[0]; }
    __syncthreads();
    const float mh = s_mh;
    float4 e1, e2;
    e1.x = __expf(d4.x - mh); e2.x = __expf(0.2f * (d4.x - mh));
    e1.y = __expf(d4.y - mh); e2.y = __expf(0.2f * (d4.y - mh));
    e1.z = __expf(d4.z - mh); e2.z = __expf(0.2f * (d4.z - mh));
    e1.w = __expf(d4.w - mh); e2.w = __expf(0.2f * (d4.w - mh));
    *(float4*)(E1 + (size_t)h * CNODES + t * 4) = e1;
    *(float4*)(E2 + (size_t)h * CNODES + t * 4) = e2;
}

// ---------------------------------------------------------------------------
// attn_pv: partial[ks][i][n] (bf16) = sum_{j in slice} w_ij * V[j][n].
// i-tile 64 (4 A-frags/wave) halves B-fragment L2/L3 traffic vs i-tile 32.
// Barrier-free K-loop; separable exp; l via ones-column MFMA; adj masks
// preloaded uint4-wide. grid (CNODES/64, KSPLIT) = 512 blocks.
// ---------------------------------------------------------------------------
__global__ __launch_bounds__(256, 2)
void attn_pv(const short* __restrict__ hbTf,
             const unsigned int* __restrict__ adjb,
             const float* __restrict__ asrc,
             const float* __restrict__ E1, const float* __restrict__ E2,
             const float* __restrict__ Mh,
             short* __restrict__ part, float* __restrict__ lpart)
{
    __shared__ __align__(16) short tileO[32][520];   // 33.3 KB (reused 2x)
    const int t    = threadIdx.x;
    const int w    = t >> 6;        // head
    const int lane = t & 63;
    const int m    = lane & 15;
    const int kq   = lane >> 4;
    const int i0   = blockIdx.x * 64;
    const int ks   = blockIdx.y;
    const int js   = ks * JPER;

    const float mh = Mh[w];
    float A1[4], A2[4], T0[4];
#pragma unroll
    for (int g = 0; g < 4; g++) {
        const float as = asrc[w * CNODES + i0 + g * 16 + m];
        const float mr = lrelu(as + mh);
        A1[g] = __expf(as + mh - mr);
        A2[g] = __expf(0.2f * (as + mh) - mr);
        T0[g] = __expf(-as - mh);
    }

    f32x4 acc[4][8], accO[4];
#pragma unroll
    for (int g = 0; g < 4; g++) {
        accO[g] = (f32x4){0.f, 0.f, 0.f, 0.f};
#pragma unroll
        for (int c = 0; c < 8; c++) acc[g][c] = (f32x4){0.f, 0.f, 0.f, 0.f};
    }
    short8 ones;
#pragma unroll
    for (int q = 0; q < 8; q++) ones[q] = (short)0x3F80;   // bf16 1.0

    for (int ch4 = 0; ch4 < 4; ch4++) {
        uint4 am[4];
#pragma unroll
        for (int g = 0; g < 4; g++)
            am[g] = *(const uint4*)(adjb + (size_t)(i0 + g * 16 + m) * 128 + ks * NCH + ch4 * 4);

#pragma unroll
        for (int chi = 0; chi < 4; chi++) {
            const int j0 = js + (ch4 * 4 + chi) * 32;
            unsigned aw[4];
#pragma unroll
            for (int g = 0; g < 4; g++)
                aw[g] = ((const unsigned*)&am[g])[chi] >> (kq * 8);

            const float4* p1 = (const float4*)(E1 + (size_t)w * CNODES + j0 + kq * 8);
            const float4* p2 = (const float4*)(E2 + (size_t)w * CNODES + j0 + kq * 8);
            const float4 x0 = p1[0], x1 = p1[1];
            const float4 y0 = p2[0], y1 = p2[1];
            const float e1v[8] = {x0.x, x0.y, x0.z, x0.w, x1.x, x1.y, x1.z, x1.w};
            const float e2v[8] = {y0.x, y0.y, y0.z, y0.w, y1.x, y1.y, y1.z, y1.w};

            short8 a[4];
#pragma unroll
            for (int q = 0; q < 8; q++) {
                const float e1 = e1v[q], e2 = e2v[q];
#pragma unroll
                for (int g = 0; g < 4; g++) {
                    const bool c0 = e1 > T0[g];
                    float wv = (c0 ? A1[g] : A2[g]) * (c0 ? e1 : e2);
                    wv = ((aw[g] >> q) & 1u) ? wv : 0.f;
                    a[g][q] = hup(wv);
                }
            }

            const short* bbase = hbTf + (((size_t)(w * 8) * 128 + (j0 >> 5)) * 64 + lane) * 8;
#pragma unroll
            for (int c = 0; c < 8; c++) {
                short8 bf = *(const short8*)(bbase + (size_t)c * 128 * 64 * 8);
                acc[0][c] = __builtin_amdgcn_mfma_f32_16x16x32_bf16(a[0], bf, acc[0][c], 0, 0, 0);
                acc[1][c] = __builtin_amdgcn_mfma_f32_16x16x32_bf16(a[1], bf, acc[1][c], 0, 0, 0);
                acc[2][c] = __builtin_amdgcn_mfma_f32_16x16x32_bf16(a[2], bf, acc[2][c], 0, 0, 0);
                acc[3][c] = __builtin_amdgcn_mfma_f32_16x16x32_bf16(a[3], bf, acc[3][c], 0, 0, 0);
            }
#pragma unroll
            for (int g = 0; g < 4; g++)
                accO[g] = __builtin_amdgcn_mfma_f32_16x16x32_bf16(a[g], ones, accO[g], 0, 0, 0);
        }
    }

    const int col = m, q4 = kq;
    if (m == 0) {
#pragma unroll
        for (int g = 0; g < 4; g++)
#pragma unroll
            for (int r = 0; r < 4; r++)
                lpart[((size_t)ks * NHEAD + w) * CNODES + i0 + g * 16 + q4 * 4 + r] = accO[g][r];
    }

    // bf16 partials via 32-row LDS tile, two rounds
    short* pS = part + (size_t)ks * CNODES * HID;
    for (int half = 0; half < 2; half++) {
        __syncthreads();
#pragma unroll
        for (int f = 0; f < 2; f++)
#pragma unroll
            for (int c = 0; c < 8; c++)
#pragma unroll
                for (int r = 0; r < 4; r++)
                    tileO[f * 16 + q4 * 4 + r][w * 128 + c * 16 + col] = f2bf(acc[half * 2 + f][c][r]);
        __syncthreads();
#pragma unroll
        for (int it = 0; it < 8; it++) {
            const int u   = it * 256 + t;
            const int row = u >> 6, un = u & 63;
            uint4 v = *(const uint4*)&tileO[row][un * 8];
            *(uint4*)&pS[(size_t)(i0 + half * 32 + row) * HID + un * 8] = v;
        }
    }
}

// ---------------------------------------------------------------------------
// reduce_norm_frag: out = (sum_s part)/(sum_s lpart), optional ELU, written
// directly as bf16 fragments.
// ---------------------------------------------------------------------------
template <bool ELU>
__global__ __launch_bounds__(256)
void reduce_norm_frag(const short* __restrict__ part, const float* __restrict__ lpart,
                      short* __restrict__ dst)
{
    const int t = threadIdx.x;
    const int W = blockIdx.x * 4 + (t >> 6);
    const int lane = t & 63;
    const int rb = W >> 4, kc = W & 15;
    const int m = lane & 15, kq = lane >> 4;
    const int i = rb * 16 + m;
    const int n0 = kc * 32 + kq * 8;
    const int h = kc >> 2;

    float v[8] = {};
    float l = 0.f;
#pragma unroll
    for (int s = 0; s < KSPLIT; s++) {
        const uint4 raw = *(const uint4*)&part[(size_t)s * CNODES * HID + (size_t)i * HID + n0];
        const unsigned rr[4] = {raw.x, raw.y, raw.z, raw.w};
#pragma unroll
        for (int q = 0; q < 4; q++) {
            v[q * 2]     += bf2f((short)(rr[q] & 0xffff));
            v[q * 2 + 1] += bf2f((short)(rr[q] >> 16));
        }
        l += lpart[((size_t)s * NHEAD + h) * CNODES + i];
    }
    const float inv = 1.0f / l;
    short8 o;
#pragma unroll
    for (int q = 0; q < 8; q++) {
        float x = v[q] * inv;
        if (ELU) x = x > 0.f ? x : (__expf(x) - 1.f);
        o[q] = f2bf(x);
    }
    *(short8*)&dst[((size_t)(rb * 16 + kc) * 64 + lane) * 8] = o;
}

// ---------------------------------------------------------------------------
extern "C" void kernel_launch(void* const* d_in, const int* in_sizes, int n_in,
                              void* d_out, int out_size, void* d_ws, size_t ws_size,
                              hipStream_t stream)
{
    const float* doc_x      = (const float*)d_in[0];
    const float* label_init = (const float*)d_in[1];
    const int*   adj        = (const int*)d_in[2];
    const float* W1         = (const float*)d_in[3];
    const float* a_src1     = (const float*)d_in[4];
    const float* a_dst1     = (const float*)d_in[5];
    const float* W2         = (const float*)d_in[6];
    const float* a_src2     = (const float*)d_in[7];
    const float* a_dst2     = (const float*)d_in[8];
    const float* Wd         = (const float*)d_in[9];
    const float* bd         = (const float*)d_in[10];
    float*       out        = (float*)d_out;

    char* wsb = (char*)d_ws;
    size_t off = 0;
    auto alloc = [&](size_t bytes) -> char* {
        char* p = wsb + off;
        off = (off + bytes + 255) & ~(size_t)255;
        return p;
    };

    float* asrc  = (float*)alloc(NHEAD * CNODES * 4);
    float* adst  = (float*)alloc(NHEAD * CNODES * 4);
    float* Mh    = (float*)alloc(256);
    float* E1    = (float*)alloc(NHEAD * CNODES * 4);
    float* E2    = (float*)alloc(NHEAD * CNODES * 4);
    float* lpart = (float*)alloc((size_t)KSPLIT * NHEAD * CNODES * 4);
    unsigned int* adjb = (unsigned int*)alloc((size_t)CNODES * 128 * 4);   // 2 MB
    short* hbTf  = (short*)alloc((size_t)CNODES * HID * 2);                // 4 MB
    short* Wdf   = (short*)alloc((size_t)INDIM * HID * 2);
    short* W1f   = (short*)alloc((size_t)INDIM * HID * 2);
    short* W2f   = (short*)alloc((size_t)HID * HID * 2);
    short* dxf   = (short*)alloc((size_t)BDOCS * INDIM * 2);
    short* Af_li = (short*)alloc((size_t)CNODES * INDIM * 2);              // 6 MB
    short* Af2   = (short*)alloc((size_t)CNODES * HID * 2);                // 4 MB
    short* lhf   = (short*)alloc((size_t)CNODES * HID * 2);                // 4 MB
    short* dhf   = (short*)alloc((size_t)BDOCS * HID * 2);                 // 1 MB
    short* part  = (short*)alloc((size_t)KSPLIT * CNODES * HID * 2);       // 32 MB
    (void)ws_size;

    const dim3 blk(256);

    // all one-time transforms in a single dispatch
    prep_all<<<PREP_BLOCKS, blk, 0, stream>>>(adj, (unsigned long long*)adjb,
                                              Wd, Wdf, W1, W1f, W2, W2f,
                                              doc_x, dxf, label_init, Af_li);

    // doc_h = relu(doc_x @ Wd + bd) -> dhf A-frags (fused)
    gemm_doc<INDIM / 32><<<dim3(BDOCS / 16, HID / 64), 64, 0, stream>>>(dxf, Wdf, bd, dhf);

    // hpre1 = label_init @ W1 -> hbTf B-frags + asrc/adst (fused)
    gemm_hpre<INDIM / 32><<<dim3(CNODES / 16, NHEAD), 64, 0, stream>>>(
        Af_li, W1f, a_src1, a_dst1, hbTf, asrc, adst);

    // GAT layer 1
    stats_exp<<<NHEAD, 1024, 0, stream>>>(adst, Mh, E1, E2);
    attn_pv<<<dim3(CNODES / 64, KSPLIT), blk, 0, stream>>>(hbTf, adjb, asrc, E1, E2, Mh, part, lpart);
    reduce_norm_frag<true><<<CNODES * HID / 256 / 8, blk, 0, stream>>>(part, lpart, Af2);

    // hpre2 = elu(gat1) @ W2 -> hbTf B-frags + asrc/adst (fused)
    gemm_hpre<HID / 32><<<dim3(CNODES / 16, NHEAD), 64, 0, stream>>>(
        Af2, W2f, a_src2, a_dst2, hbTf, asrc, adst);

    // GAT layer 2
    stats_exp<<<NHEAD, 1024, 0, stream>>>(adst, Mh, E1, E2);
    attn_pv<<<dim3(CNODES / 64, KSPLIT), blk, 0, stream>>>(hbTf, adjb, asrc, E1, E2, Mh, part, lpart);
    reduce_norm_frag<false><<<CNODES * HID / 256 / 8, blk, 0, stream>>>(part, lpart, lhf);

    // logits = doc_h @ label_h^T -> out
    gemm_frag<HID / 32><<<dim3(BDOCS / 32, CNODES / 128), 64, 0, stream>>>(dhf, lhf, out, CNODES);
}

// Round 9
// 394.129 us; speedup vs baseline: 1.0162x; 1.0162x over previous
//
#include <hip/hip_runtime.h>
#include <hip/hip_bf16.h>
#include <math.h>

// Shapes are fixed by the problem instance.
#define BDOCS   1024
#define CNODES  4096
#define INDIM   768
#define HID     512
#define NHEAD   4
#define HDIM    128
#define NEG_SLOPE 0.2f

#define KSPLIT  8
#define JPER    (CNODES / KSPLIT)   // 512
#define NCH     (JPER / 32)         // 16

typedef __attribute__((ext_vector_type(8))) short short8;   // 8 bf16 (4 VGPRs)
typedef __attribute__((ext_vector_type(4))) float f32x4;    // MFMA C/D

__device__ __forceinline__ float lrelu(float x) { return x > 0.f ? x : NEG_SLOPE * x; }

// float -> bf16 bits, round-to-nearest-even
__device__ __forceinline__ short f2bf(float f) {
    union { float f; unsigned u; } v; v.f = f;
    unsigned r = (v.u + 0x7fff + ((v.u >> 16) & 1)) >> 16;
    return (short)r;
}
__device__ __forceinline__ float bf2f(short s) {
    union { float f; unsigned u; } v; v.u = ((unsigned)(unsigned short)s) << 16;
    return v.f;
}
__device__ __forceinline__ unsigned pk2(float a, float b) {
    union { float f; unsigned u; } x, y; x.f = a; y.f = b;
    unsigned lo = (x.u + 0x7fff + ((x.u >> 16) & 1)) >> 16;
    unsigned hi = (y.u + 0x7fff + ((y.u >> 16) & 1)) >> 16;
    return lo | (hi << 16);
}
// half-up round f32 -> bf16 (hot loop; w in [0,1])
__device__ __forceinline__ short hup(float f) {
    union { float f; unsigned u; } v; v.f = f;
    return (short)((v.u + 0x8000) >> 16);
}
// monotone float<->uint encoding for atomicMax on floats
__device__ __forceinline__ unsigned encf(float x) {
    union { float f; unsigned u; } v; v.f = x;
    return (v.u & 0x80000000u) ? ~v.u : (v.u | 0x80000000u);
}
__device__ __forceinline__ float decf(unsigned u) {
    union { float f; unsigned u; } v;
    v.u = (u & 0x80000000u) ? (u ^ 0x80000000u) : ~u;
    return v.f;
}

// ---------------------------------------------------------------------------
// prep helpers as device functions (shared LDS tile passed in)
// ---------------------------------------------------------------------------
__device__ void frag_T_dev(const float* __restrict__ src, short* __restrict__ dst,
                           int N, int K, int jc, int nq, float (*tile)[132])
{
    const int t  = threadIdx.x;
    const int KC = K >> 5;
#pragma unroll
    for (int it = 0; it < 16; it++) {
        const int e = it * 256 + t;
        const int j = e >> 7, n = e & 127;
        tile[j][n] = src[(size_t)(jc * 32 + j) * N + nq * 128 + n];
    }
    __syncthreads();
#pragma unroll
    for (int s = 0; s < 2; s++) {
        const int item = s * 256 + t;
        const int nbl = item >> 6, lane = item & 63;
        const int nr = lane & 15, kq = lane >> 4;
        short8 v;
#pragma unroll
        for (int jr = 0; jr < 8; jr++)
            v[jr] = f2bf(tile[kq * 8 + jr][nbl * 16 + nr]);
        *(short8*)&dst[((size_t)((nq * 8 + nbl) * KC + jc) * 64 + lane) * 8] = v;
    }
}

__device__ void frag_A_dev(const float* __restrict__ src, short* __restrict__ dst,
                           int C, int rb, int cq, float (*tile)[132])
{
    const int t  = threadIdx.x;
    const int KC = C >> 5;
#pragma unroll
    for (int it = 0; it < 8; it++) {
        const int e = it * 256 + t;
        const int r = e >> 7, c = e & 127;
        tile[r][c] = src[(size_t)(rb * 16 + r) * C + cq * 128 + c];
    }
    __syncthreads();
    const int kcl = t >> 6, lane = t & 63;
    const int m = lane & 15, kq = lane >> 4;
    short8 v8;
#pragma unroll
    for (int j = 0; j < 8; j++) v8[j] = f2bf(tile[m][kcl * 32 + kq * 8 + j]);
    *(short8*)&dst[((size_t)(rb * KC + cq * 4 + kcl) * 64 + lane) * 8] = v8;
}

// ---------------------------------------------------------------------------
// prep_all: pack_adj (65536 blocks) + frag_T(Wd/W1/W2) + frag_A(doc_x,
// label_init), flattened into one grid. Also zero-inits the 8 MhEnc slots.
// ---------------------------------------------------------------------------
#define PREP_BLOCKS (65536 + 96 + 96 + 64 + 384 + 1536)
__global__ __launch_bounds__(256)
void prep_all(const int* __restrict__ adj, unsigned long long* __restrict__ adjb64,
              const float* __restrict__ Wd, short* __restrict__ Wdf,
              const float* __restrict__ W1, short* __restrict__ W1f,
              const float* __restrict__ W2, short* __restrict__ W2f,
              const float* __restrict__ doc_x, short* __restrict__ dxf,
              const float* __restrict__ label_init, short* __restrict__ lif,
              unsigned* __restrict__ MhEnc)
{
    __shared__ float tile[32][132];
    int b = blockIdx.x;
    if (b < 65536) {
        if (b == 0 && threadIdx.x < 8) MhEnc[threadIdx.x] = 0u;
        const int t    = threadIdx.x;
        const int gw   = b * 4 + (t >> 6);
        const int lane = t & 63;
        const int i  = gw >> 6;
        const int j0 = (gw & 63) * 64;
        const int a  = adj[(size_t)i * CNODES + j0 + lane];
        const unsigned long long msk = __ballot(a != 0);
        if (lane == 0) adjb64[(size_t)i * 64 + (j0 >> 6)] = msk;
        return;
    }
    b -= 65536;
    if (b < 96)  { frag_T_dev(Wd, Wdf, HID, INDIM, b % 24, b / 24, tile); return; }
    b -= 96;
    if (b < 96)  { frag_T_dev(W1, W1f, HID, INDIM, b % 24, b / 24, tile); return; }
    b -= 96;
    if (b < 64)  { frag_T_dev(W2, W2f, HID, HID, b % 16, b / 16, tile); return; }
    b -= 64;
    if (b < 384) { frag_A_dev(doc_x, dxf, INDIM, b % 64, b / 64, tile); return; }
    b -= 384;
    frag_A_dev(label_init, lif, INDIM, b % 256, b / 256, tile);
}

// ---------------------------------------------------------------------------
// gemm_hpre: hpre tile = A @ B^T. m-tile 16 -> grid (CNODES/16, NHEAD).
// Epilogue: (a) half-B-frags of bf16(hpre) -> hbTf, (b) asrc/adst row dots,
// (c) wave-max of adst -> atomicMax into MhEnc[nq] (monotone uint encoding).
// ---------------------------------------------------------------------------
template <int KC>
__global__ __launch_bounds__(64)
void gemm_hpre(const short* __restrict__ Af, const short* __restrict__ Bf,
               const float* __restrict__ a_src, const float* __restrict__ a_dst,
               short* __restrict__ hbTf, float* __restrict__ asrc, float* __restrict__ adst,
               unsigned* __restrict__ MhEnc)
{
    __shared__ __align__(16) short tileT[128][24];   // [col][localrow]
    const int lane = threadIdx.x;
    const int mb   = blockIdx.x;       // 0..255
    const int nq   = blockIdx.y;       // head
    const int i0   = mb * 16;

    f32x4 acc[8];
#pragma unroll
    for (int c = 0; c < 8; c++) acc[c] = (f32x4){0.f, 0.f, 0.f, 0.f};

    const short* ap = Af + (size_t)mb * KC * 512 + lane * 8;
    const short* bp = Bf + (size_t)(nq * 8) * KC * 512 + lane * 8;

#pragma unroll 2
    for (int kc = 0; kc < KC; kc++) {
        short8 a = *(const short8*)(ap + (size_t)kc * 512);
#pragma unroll
        for (int c = 0; c < 8; c++) {
            short8 bf = *(const short8*)(bp + ((size_t)c * KC + kc) * 512);
            acc[c] = __builtin_amdgcn_mfma_f32_16x16x32_bf16(a, bf, acc[c], 0, 0, 0);
        }
    }

    const int col = lane & 15, q4 = lane >> 4;

#pragma unroll
    for (int c = 0; c < 8; c++) {
        uint2 u;
        u.x = pk2(acc[c][0], acc[c][1]);
        u.y = pk2(acc[c][2], acc[c][3]);
        *(uint2*)&tileT[c * 16 + col][q4 * 4] = u;
    }
    __syncthreads();
    {
        const int jc = mb >> 1, khalf = mb & 1;
        const int nr = lane & 15, kq = lane >> 4;
        if ((kq >> 1) == khalf) {
#pragma unroll
            for (int nbl = 0; nbl < 8; nbl++) {
                short8 v = *(const short8*)&tileT[nbl * 16 + nr][(kq & 1) * 8];
                *(short8*)&hbTf[(((size_t)(nq * 8 + nbl) * (CNODES / 32) + jc) * 64 + lane) * 8] = v;
            }
        }
    }

    float ssrc[4] = {}, sdst[4] = {};
#pragma unroll
    for (int c = 0; c < 8; c++) {
        const float vs = a_src[nq * 128 + c * 16 + col];
        const float vd = a_dst[nq * 128 + c * 16 + col];
#pragma unroll
        for (int r = 0; r < 4; r++) {
            ssrc[r] += acc[c][r] * vs;
            sdst[r] += acc[c][r] * vd;
        }
    }
#pragma unroll
    for (int mask = 1; mask <= 8; mask <<= 1)
#pragma unroll
        for (int r = 0; r < 4; r++) {
            ssrc[r] += __shfl_xor(ssrc[r], mask);
            sdst[r] += __shfl_xor(sdst[r], mask);
        }
    if (col == 0) {
#pragma unroll
        for (int r = 0; r < 4; r++) {
            const int row = i0 + q4 * 4 + r;
            asrc[nq * CNODES + row] = ssrc[r];
            adst[nq * CNODES + row] = sdst[r];
        }
    }
    // wave max of adst tile -> one atomic per block
    float wmax = fmaxf(fmaxf(sdst[0], sdst[1]), fmaxf(sdst[2], sdst[3]));
    wmax = fmaxf(wmax, __shfl_xor(wmax, 16));
    wmax = fmaxf(wmax, __shfl_xor(wmax, 32));
    if (lane == 0) atomicMax(MhEnc + nq, encf(wmax));
}

// ---------------------------------------------------------------------------
// gemm_doc: doc_h tile = relu(A @ B^T + bias) -> bf16 A-frags (dhf).
// ---------------------------------------------------------------------------
template <int KC>
__global__ __launch_bounds__(64)
void gemm_doc(const short* __restrict__ Af, const short* __restrict__ Bf,
              const float* __restrict__ bias, short* __restrict__ dhf)
{
    __shared__ __align__(16) short tile[16][64];
    const int lane = threadIdx.x;
    const int mb = blockIdx.x;
    const int ng = blockIdx.y;

    f32x4 acc[4];
#pragma unroll
    for (int c = 0; c < 4; c++) acc[c] = (f32x4){0.f, 0.f, 0.f, 0.f};

    const short* ap = Af + (size_t)mb * KC * 512 + lane * 8;
    const short* bp = Bf + (size_t)(ng * 4) * KC * 512 + lane * 8;

#pragma unroll 2
    for (int kc = 0; kc < KC; kc++) {
        short8 a = *(const short8*)(ap + (size_t)kc * 512);
#pragma unroll
        for (int c = 0; c < 4; c++) {
            short8 bf = *(const short8*)(bp + ((size_t)c * KC + kc) * 512);
            acc[c] = __builtin_amdgcn_mfma_f32_16x16x32_bf16(a, bf, acc[c], 0, 0, 0);
        }
    }

    const int col = lane & 15, q4 = lane >> 4;
#pragma unroll
    for (int c = 0; c < 4; c++)
#pragma unroll
        for (int r = 0; r < 4; r++) {
            float v = fmaxf(acc[c][r] + bias[ng * 64 + c * 16 + col], 0.f);
            tile[q4 * 4 + r][c * 16 + col] = f2bf(v);
        }
    __syncthreads();
    const int m = lane & 15, kq = lane >> 4;
#pragma unroll
    for (int kcl = 0; kcl < 2; kcl++) {
        short8 v = *(const short8*)&tile[m][kcl * 32 + kq * 8];
        *(short8*)&dhf[(((size_t)mb * 16 + ng * 2 + kcl) * 64 + lane) * 8] = v;
    }
}

// ---------------------------------------------------------------------------
// gemm_frag: C[M][N] fp32 = A @ B^T from bf16 fragments (logits).
// ---------------------------------------------------------------------------
template <int KC>
__global__ __launch_bounds__(64)
void gemm_frag(const short* __restrict__ Af, const short* __restrict__ Bf,
               float* __restrict__ Cmat, int N)
{
    const int lane = threadIdx.x;
    const int mb0  = blockIdx.x * 2;
    const int nq   = blockIdx.y;

    f32x4 acc[2][8];
#pragma unroll
    for (int f = 0; f < 2; f++)
#pragma unroll
        for (int c = 0; c < 8; c++) acc[f][c] = (f32x4){0.f, 0.f, 0.f, 0.f};

    const short* ap0 = Af + (size_t)mb0 * KC * 512 + lane * 8;
    const short* ap1 = ap0 + (size_t)KC * 512;
    const short* bp  = Bf + (size_t)(nq * 8) * KC * 512 + lane * 8;

#pragma unroll 2
    for (int kc = 0; kc < KC; kc++) {
        short8 a0 = *(const short8*)(ap0 + (size_t)kc * 512);
        short8 a1 = *(const short8*)(ap1 + (size_t)kc * 512);
#pragma unroll
        for (int c = 0; c < 8; c++) {
            short8 bf = *(const short8*)(bp + ((size_t)c * KC + kc) * 512);
            acc[0][c] = __builtin_amdgcn_mfma_f32_16x16x32_bf16(a0, bf, acc[0][c], 0, 0, 0);
            acc[1][c] = __builtin_amdgcn_mfma_f32_16x16x32_bf16(a1, bf, acc[1][c], 0, 0, 0);
        }
    }

    const int col = lane & 15, q4 = lane >> 4;
#pragma unroll
    for (int f = 0; f < 2; f++)
#pragma unroll
        for (int c = 0; c < 8; c++)
#pragma unroll
            for (int r = 0; r < 4; r++) {
                const int row = (mb0 + f) * 16 + q4 * 4 + r;
                Cmat[(size_t)row * N + nq * 128 + c * 16 + col] = acc[f][c][r];
            }
}

// ---------------------------------------------------------------------------
// attn_pv: partial[ks][i][n] (bf16) = sum_{j in slice} w_ij * V[j][n].
// 512-thread blocks = 8 waves: wave (f2,w) handles i-rows [i0+f2*32, +32) of
// head w with the proven R7 inner loop (2 A-frags/wave). E1/E2 computed into
// LDS in a preamble (deletes stats_exp). grid (CNODES/64, KSPLIT) = 512
// blocks x 8 waves = 16 waves/CU at (512,2).
// ---------------------------------------------------------------------------
__global__ __launch_bounds__(512, 2)
void attn_pv(const short* __restrict__ hbTf,
             const unsigned int* __restrict__ adjb,
             const float* __restrict__ asrc, const float* __restrict__ adst,
             const unsigned* __restrict__ MhEnc,
             short* __restrict__ part, float* __restrict__ lpart)
{
    __shared__ __align__(16) float E1s[NHEAD][512];    // 8 KB
    __shared__ __align__(16) float E2s[NHEAD][512];    // 8 KB
    __shared__ __align__(16) short tileO[32][520];     // 33.3 KB

    const int t    = threadIdx.x;
    const int ww   = t >> 6;
    const int w    = ww & 3;        // head
    const int f2   = ww >> 2;       // i-half (0/1)
    const int lane = t & 63;
    const int m    = lane & 15;
    const int kq   = lane >> 4;
    const int i0   = blockIdx.x * 64;
    const int iw   = i0 + f2 * 32;
    const int ks   = blockIdx.y;
    const int js   = ks * JPER;

    // ---- preamble: E1/E2 for this slice into LDS (t indexes j) ----
    {
        const int j = js + t;
#pragma unroll
        for (int h = 0; h < NHEAD; h++) {
            const float d = adst[h * CNODES + j] - decf(MhEnc[h]);
            E1s[h][t] = __expf(d);
            E2s[h][t] = __expf(0.2f * d);
        }
    }

    const float mh  = decf(MhEnc[w]);
    const float as0 = asrc[w * CNODES + iw + m];
    const float as1 = asrc[w * CNODES + iw + 16 + m];
    const float mr0 = lrelu(as0 + mh), mr1 = lrelu(as1 + mh);
    const float A10 = __expf(as0 + mh - mr0),          A11 = __expf(as1 + mh - mr1);
    const float A20 = __expf(0.2f * (as0 + mh) - mr0), A21 = __expf(0.2f * (as1 + mh) - mr1);
    const float T00 = __expf(-as0 - mh),               T01 = __expf(-as1 - mh);

    f32x4 acc[2][8], accO[2];
#pragma unroll
    for (int f = 0; f < 2; f++) {
        accO[f] = (f32x4){0.f, 0.f, 0.f, 0.f};
#pragma unroll
        for (int c = 0; c < 8; c++) acc[f][c] = (f32x4){0.f, 0.f, 0.f, 0.f};
    }
    short8 ones;
#pragma unroll
    for (int q = 0; q < 8; q++) ones[q] = (short)0x3F80;   // bf16 1.0

    const unsigned int* ar0 = adjb + (size_t)(iw + m) * 128 + ks * NCH;
    const unsigned int* ar1 = adjb + (size_t)(iw + 16 + m) * 128 + ks * NCH;

    __syncthreads();   // E LDS ready

#pragma unroll 2
    for (int ch = 0; ch < NCH; ch++) {
        const int jl = ch * 32;
        const unsigned int aw0 = ar0[ch] >> (kq * 8);
        const unsigned int aw1 = ar1[ch] >> (kq * 8);
        const float4 x0 = *(const float4*)&E1s[w][jl + kq * 8];
        const float4 x1 = *(const float4*)&E1s[w][jl + kq * 8 + 4];
        const float4 y0 = *(const float4*)&E2s[w][jl + kq * 8];
        const float4 y1 = *(const float4*)&E2s[w][jl + kq * 8 + 4];
        const float e1v[8] = {x0.x, x0.y, x0.z, x0.w, x1.x, x1.y, x1.z, x1.w};
        const float e2v[8] = {y0.x, y0.y, y0.z, y0.w, y1.x, y1.y, y1.z, y1.w};

        short8 a0, a1;
#pragma unroll
        for (int q = 0; q < 8; q++) {
            const float e1 = e1v[q], e2 = e2v[q];
            const bool c0 = e1 > T00, c1 = e1 > T01;
            float w0 = (c0 ? A10 : A20) * (c0 ? e1 : e2);
            float w1 = (c1 ? A11 : A21) * (c1 ? e1 : e2);
            w0 = ((aw0 >> q) & 1u) ? w0 : 0.f;
            w1 = ((aw1 >> q) & 1u) ? w1 : 0.f;
            a0[q] = hup(w0);
            a1[q] = hup(w1);
        }

        const short* bbase = hbTf + (((size_t)(w * 8) * 128 + ((js + jl) >> 5)) * 64 + lane) * 8;
#pragma unroll
        for (int c = 0; c < 8; c++) {
            short8 bf = *(const short8*)(bbase + (size_t)c * 128 * 64 * 8);
            acc[0][c] = __builtin_amdgcn_mfma_f32_16x16x32_bf16(a0, bf, acc[0][c], 0, 0, 0);
            acc[1][c] = __builtin_amdgcn_mfma_f32_16x16x32_bf16(a1, bf, acc[1][c], 0, 0, 0);
        }
        accO[0] = __builtin_amdgcn_mfma_f32_16x16x32_bf16(a0, ones, accO[0], 0, 0, 0);
        accO[1] = __builtin_amdgcn_mfma_f32_16x16x32_bf16(a1, ones, accO[1], 0, 0, 0);
    }

    if (m == 0) {
#pragma unroll
        for (int f = 0; f < 2; f++)
#pragma unroll
            for (int r = 0; r < 4; r++)
                lpart[((size_t)ks * NHEAD + w) * CNODES + iw + f * 16 + kq * 4 + r] = accO[f][r];
    }

    // bf16 partials via 32-row LDS tile, one round per i-half
    short* pS = part + (size_t)ks * CNODES * HID;
    for (int half = 0; half < 2; half++) {
        __syncthreads();
        if (f2 == half) {
#pragma unroll
            for (int f = 0; f < 2; f++)
#pragma unroll
                for (int c = 0; c < 8; c++)
#pragma unroll
                    for (int r = 0; r < 4; r++)
                        tileO[f * 16 + kq * 4 + r][w * 128 + c * 16 + m] = f2bf(acc[f][c][r]);
        }
        __syncthreads();
#pragma unroll
        for (int it = 0; it < 4; it++) {
            const int u   = it * 512 + t;
            const int row = u >> 6, un = u & 63;
            uint4 v = *(const uint4*)&tileO[row][un * 8];
            *(uint4*)&pS[(size_t)(i0 + half * 32 + row) * HID + un * 8] = v;
        }
    }
}

// ---------------------------------------------------------------------------
// reduce_norm_frag: out = (sum_s part)/(sum_s lpart), optional ELU, written
// directly as bf16 fragments.
// ---------------------------------------------------------------------------
template <bool ELU>
__global__ __launch_bounds__(256)
void reduce_norm_frag(const short* __restrict__ part, const float* __restrict__ lpart,
                      short* __restrict__ dst)
{
    const int t = threadIdx.x;
    const int W = blockIdx.x * 4 + (t >> 6);
    const int lane = t & 63;
    const int rb = W >> 4, kc = W & 15;
    const int m = lane & 15, kq = lane >> 4;
    const int i = rb * 16 + m;
    const int n0 = kc * 32 + kq * 8;
    const int h = kc >> 2;

    float v[8] = {};
    float l = 0.f;
#pragma unroll
    for (int s = 0; s < KSPLIT; s++) {
        const uint4 raw = *(const uint4*)&part[(size_t)s * CNODES * HID + (size_t)i * HID + n0];
        const unsigned rr[4] = {raw.x, raw.y, raw.z, raw.w};
#pragma unroll
        for (int q = 0; q < 4; q++) {
            v[q * 2]     += bf2f((short)(rr[q] & 0xffff));
            v[q * 2 + 1] += bf2f((short)(rr[q] >> 16));
        }
        l += lpart[((size_t)s * NHEAD + h) * CNODES + i];
    }
    const float inv = 1.0f / l;
    short8 o;
#pragma unroll
    for (int q = 0; q < 8; q++) {
        float x = v[q] * inv;
        if (ELU) x = x > 0.f ? x : (__expf(x) - 1.f);
        o[q] = f2bf(x);
    }
    *(short8*)&dst[((size_t)(rb * 16 + kc) * 64 + lane) * 8] = o;
}

// ---------------------------------------------------------------------------
extern "C" void kernel_launch(void* const* d_in, const int* in_sizes, int n_in,
                              void* d_out, int out_size, void* d_ws, size_t ws_size,
                              hipStream_t stream)
{
    const float* doc_x      = (const float*)d_in[0];
    const float* label_init = (const float*)d_in[1];
    const int*   adj        = (const int*)d_in[2];
    const float* W1         = (const float*)d_in[3];
    const float* a_src1     = (const float*)d_in[4];
    const float* a_dst1     = (const float*)d_in[5];
    const float* W2         = (const float*)d_in[6];
    const float* a_src2     = (const float*)d_in[7];
    const float* a_dst2     = (const float*)d_in[8];
    const float* Wd         = (const float*)d_in[9];
    const float* bd         = (const float*)d_in[10];
    float*       out        = (float*)d_out;

    char* wsb = (char*)d_ws;
    size_t off = 0;
    auto alloc = [&](size_t bytes) -> char* {
        char* p = wsb + off;
        off = (off + bytes + 255) & ~(size_t)255;
        return p;
    };

    float* asrc  = (float*)alloc(NHEAD * CNODES * 4);
    float* adst  = (float*)alloc(NHEAD * CNODES * 4);
    unsigned* MhEnc = (unsigned*)alloc(256);          // slots 0..3 L1, 4..7 L2
    float* lpart = (float*)alloc((size_t)KSPLIT * NHEAD * CNODES * 4);
    unsigned int* adjb = (unsigned int*)alloc((size_t)CNODES * 128 * 4);   // 2 MB
    short* hbTf  = (short*)alloc((size_t)CNODES * HID * 2);                // 4 MB
    short* Wdf   = (short*)alloc((size_t)INDIM * HID * 2);
    short* W1f   = (short*)alloc((size_t)INDIM * HID * 2);
    short* W2f   = (short*)alloc((size_t)HID * HID * 2);
    short* dxf   = (short*)alloc((size_t)BDOCS * INDIM * 2);
    short* Af_li = (short*)alloc((size_t)CNODES * INDIM * 2);              // 6 MB
    short* Af2   = (short*)alloc((size_t)CNODES * HID * 2);                // 4 MB
    short* lhf   = (short*)alloc((size_t)CNODES * HID * 2);                // 4 MB
    short* dhf   = (short*)alloc((size_t)BDOCS * HID * 2);                 // 1 MB
    short* part  = (short*)alloc((size_t)KSPLIT * CNODES * HID * 2);       // 32 MB
    (void)ws_size;

    const dim3 blk(256);

    // all one-time transforms in a single dispatch (also inits MhEnc)
    prep_all<<<PREP_BLOCKS, blk, 0, stream>>>(adj, (unsigned long long*)adjb,
                                              Wd, Wdf, W1, W1f, W2, W2f,
                                              doc_x, dxf, label_init, Af_li, MhEnc);

    // doc_h = relu(doc_x @ Wd + bd) -> dhf A-frags (fused)
    gemm_doc<INDIM / 32><<<dim3(BDOCS / 16, HID / 64), 64, 0, stream>>>(dxf, Wdf, bd, dhf);

    // hpre1 = label_init @ W1 -> hbTf B-frags + asrc/adst + Mh (fused)
    gemm_hpre<INDIM / 32><<<dim3(CNODES / 16, NHEAD), 64, 0, stream>>>(
        Af_li, W1f, a_src1, a_dst1, hbTf, asrc, adst, MhEnc);

    // GAT layer 1
    attn_pv<<<dim3(CNODES / 64, KSPLIT), 512, 0, stream>>>(
        hbTf, adjb, asrc, adst, MhEnc, part, lpart);
    reduce_norm_frag<true><<<CNODES * HID / 256 / 8, blk, 0, stream>>>(part, lpart, Af2);

    // hpre2 = elu(gat1) @ W2 -> hbTf B-frags + asrc/adst + Mh (fused)
    gemm_hpre<HID / 32><<<dim3(CNODES / 16, NHEAD), 64, 0, stream>>>(
        Af2, W2f, a_src2, a_dst2, hbTf, asrc, adst, MhEnc + 4);

    // GAT layer 2
    attn_pv<<<dim3(CNODES / 64, KSPLIT), 512, 0, stream>>>(
        hbTf, adjb, asrc, adst, MhEnc + 4, part, lpart);
    reduce_norm_frag<false><<<CNODES * HID / 256 / 8, blk, 0, stream>>>(part, lpart, lhf);

    // logits = doc_h @ label_h^T -> out
    gemm_frag<HID / 32><<<dim3(BDOCS / 32, CNODES / 128), 64, 0, stream>>>(dhf, lhf, out, CNODES);
}

// Round 10
// 357.448 us; speedup vs baseline: 1.1205x; 1.1026x over previous
//
#include <hip/hip_runtime.h>
#include <hip/hip_bf16.h>
#include <math.h>

// Shapes are fixed by the problem instance.
#define BDOCS   1024
#define CNODES  4096
#define INDIM   768
#define HID     512
#define NHEAD   4
#define HDIM    128
#define NEG_SLOPE 0.2f

#define KSPLIT  8
#define JPER    (CNODES / KSPLIT)   // 512
#define NCH     (JPER / 32)         // 16

typedef __attribute__((ext_vector_type(8))) short short8;   // 8 bf16 (4 VGPRs)
typedef __attribute__((ext_vector_type(4))) float f32x4;    // MFMA C/D

__device__ __forceinline__ float lrelu(float x) { return x > 0.f ? x : NEG_SLOPE * x; }

// float -> bf16 bits, round-to-nearest-even
__device__ __forceinline__ short f2bf(float f) {
    union { float f; unsigned u; } v; v.f = f;
    unsigned r = (v.u + 0x7fff + ((v.u >> 16) & 1)) >> 16;
    return (short)r;
}
__device__ __forceinline__ float bf2f(short s) {
    union { float f; unsigned u; } v; v.u = ((unsigned)(unsigned short)s) << 16;
    return v.f;
}
__device__ __forceinline__ unsigned pk2(float a, float b) {
    union { float f; unsigned u; } x, y; x.f = a; y.f = b;
    unsigned lo = (x.u + 0x7fff + ((x.u >> 16) & 1)) >> 16;
    unsigned hi = (y.u + 0x7fff + ((y.u >> 16) & 1)) >> 16;
    return lo | (hi << 16);
}
// half-up round f32 -> bf16 (hot loop; w in [0,1])
__device__ __forceinline__ short hup(float f) {
    union { float f; unsigned u; } v; v.f = f;
    return (short)((v.u + 0x8000) >> 16);
}
// monotone float<->uint encoding for atomicMax on floats
__device__ __forceinline__ unsigned encf(float x) {
    union { float f; unsigned u; } v; v.f = x;
    return (v.u & 0x80000000u) ? ~v.u : (v.u | 0x80000000u);
}
__device__ __forceinline__ float decf(unsigned u) {
    union { float f; unsigned u; } v;
    v.u = (u & 0x80000000u) ? (u ^ 0x80000000u) : ~u;
    return v.f;
}

// ---------------------------------------------------------------------------
// prep helpers as device functions (shared LDS tile passed in)
// ---------------------------------------------------------------------------
__device__ void frag_T_dev(const float* __restrict__ src, short* __restrict__ dst,
                           int N, int K, int jc, int nq, float (*tile)[132])
{
    const int t  = threadIdx.x;
    const int KC = K >> 5;
#pragma unroll
    for (int it = 0; it < 16; it++) {
        const int e = it * 256 + t;
        const int j = e >> 7, n = e & 127;
        tile[j][n] = src[(size_t)(jc * 32 + j) * N + nq * 128 + n];
    }
    __syncthreads();
#pragma unroll
    for (int s = 0; s < 2; s++) {
        const int item = s * 256 + t;
        const int nbl = item >> 6, lane = item & 63;
        const int nr = lane & 15, kq = lane >> 4;
        short8 v;
#pragma unroll
        for (int jr = 0; jr < 8; jr++)
            v[jr] = f2bf(tile[kq * 8 + jr][nbl * 16 + nr]);
        *(short8*)&dst[((size_t)((nq * 8 + nbl) * KC + jc) * 64 + lane) * 8] = v;
    }
}

__device__ void frag_A_dev(const float* __restrict__ src, short* __restrict__ dst,
                           int C, int rb, int cq, float (*tile)[132])
{
    const int t  = threadIdx.x;
    const int KC = C >> 5;
#pragma unroll
    for (int it = 0; it < 8; it++) {
        const int e = it * 256 + t;
        const int r = e >> 7, c = e & 127;
        tile[r][c] = src[(size_t)(rb * 16 + r) * C + cq * 128 + c];
    }
    __syncthreads();
    const int kcl = t >> 6, lane = t & 63;
    const int m = lane & 15, kq = lane >> 4;
    short8 v8;
#pragma unroll
    for (int j = 0; j < 8; j++) v8[j] = f2bf(tile[m][kcl * 32 + kq * 8 + j]);
    *(short8*)&dst[((size_t)(rb * KC + cq * 4 + kcl) * 64 + lane) * 8] = v8;
}

// ---------------------------------------------------------------------------
// prep_all: pack_adj (65536 blocks) + frag_T(Wd/W1/W2) + frag_A(doc_x,
// label_init), flattened into one grid. Inits the 16 MhEnc slots to enc(-inf).
// ---------------------------------------------------------------------------
#define PREP_BLOCKS (65536 + 96 + 96 + 64 + 384 + 1536)
__global__ __launch_bounds__(256)
void prep_all(const int* __restrict__ adj, unsigned long long* __restrict__ adjb64,
              const float* __restrict__ Wd, short* __restrict__ Wdf,
              const float* __restrict__ W1, short* __restrict__ W1f,
              const float* __restrict__ W2, short* __restrict__ W2f,
              const float* __restrict__ doc_x, short* __restrict__ dxf,
              const float* __restrict__ label_init, short* __restrict__ lif,
              unsigned* __restrict__ MhEnc)
{
    __shared__ float tile[32][132];
    int b = blockIdx.x;
    if (b < 65536) {
        if (b == 0 && threadIdx.x < 16) MhEnc[threadIdx.x] = 0x007FFFFFu;  // enc(-inf)
        const int t    = threadIdx.x;
        const int gw   = b * 4 + (t >> 6);
        const int lane = t & 63;
        const int i  = gw >> 6;
        const int j0 = (gw & 63) * 64;
        const int a  = adj[(size_t)i * CNODES + j0 + lane];
        const unsigned long long msk = __ballot(a != 0);
        if (lane == 0) adjb64[(size_t)i * 64 + (j0 >> 6)] = msk;
        return;
    }
    b -= 65536;
    if (b < 96)  { frag_T_dev(Wd, Wdf, HID, INDIM, b % 24, b / 24, tile); return; }
    b -= 96;
    if (b < 96)  { frag_T_dev(W1, W1f, HID, INDIM, b % 24, b / 24, tile); return; }
    b -= 96;
    if (b < 64)  { frag_T_dev(W2, W2f, HID, HID, b % 16, b / 16, tile); return; }
    b -= 64;
    if (b < 384) { frag_A_dev(doc_x, dxf, INDIM, b % 64, b / 64, tile); return; }
    b -= 384;
    frag_A_dev(label_init, lif, INDIM, b % 256, b / 256, tile);
}

// ---------------------------------------------------------------------------
// gemm_hpre: hpre tile = A @ B^T, n-split by half-head. grid (CNODES/16, 8):
// blockIdx.y = h*2+ch covers cols [h*128+ch*64, +64) (4 B-frags, 5 loads/kc).
// Epilogue: (a) half-B-frags of bf16(hpre) -> hbTf, (b) asrc/adst half-dots
// -> deterministic 2-way atomicAdd, (c) wave max of half-dot -> atomicMax
// MhEncH[h*2+ch] (sum of half maxima is a valid softmax shift bound).
// ---------------------------------------------------------------------------
template <int KC>
__global__ __launch_bounds__(64)
void gemm_hpre(const short* __restrict__ Af, const short* __restrict__ Bf,
               const float* __restrict__ a_src, const float* __restrict__ a_dst,
               short* __restrict__ hbTf, float* __restrict__ asrc, float* __restrict__ adst,
               unsigned* __restrict__ MhEncH)
{
    __shared__ __align__(16) short tileT[64][24];   // [localcol][localrow]
    const int lane = threadIdx.x;
    const int mb   = blockIdx.x;        // 0..255
    const int h    = blockIdx.y >> 1;   // head
    const int ch   = blockIdx.y & 1;    // col half
    const int i0   = mb * 16;

    f32x4 acc[4];
#pragma unroll
    for (int c = 0; c < 4; c++) acc[c] = (f32x4){0.f, 0.f, 0.f, 0.f};

    const short* ap = Af + (size_t)mb * KC * 512 + lane * 8;
    const short* bp = Bf + (size_t)(h * 8 + ch * 4) * KC * 512 + lane * 8;

#pragma unroll 2
    for (int kc = 0; kc < KC; kc++) {
        short8 a = *(const short8*)(ap + (size_t)kc * 512);
#pragma unroll
        for (int c = 0; c < 4; c++) {
            short8 bf = *(const short8*)(bp + ((size_t)c * KC + kc) * 512);
            acc[c] = __builtin_amdgcn_mfma_f32_16x16x32_bf16(a, bf, acc[c], 0, 0, 0);
        }
    }

    const int col = lane & 15, q4 = lane >> 4;

#pragma unroll
    for (int c = 0; c < 4; c++) {
        uint2 u;
        u.x = pk2(acc[c][0], acc[c][1]);
        u.y = pk2(acc[c][2], acc[c][3]);
        *(uint2*)&tileT[c * 16 + col][q4 * 4] = u;
    }
    __syncthreads();
    {
        const int jc = mb >> 1, khalf = mb & 1;
        const int nr = lane & 15, kq = lane >> 4;
        if ((kq >> 1) == khalf) {
#pragma unroll
            for (int cl = 0; cl < 4; cl++) {
                short8 v = *(const short8*)&tileT[cl * 16 + nr][(kq & 1) * 8];
                const int nbl = h * 8 + ch * 4 + cl;
                *(short8*)&hbTf[(((size_t)nbl * (CNODES / 32) + jc) * 64 + lane) * 8] = v;
            }
        }
    }

    float ssrc[4] = {}, sdst[4] = {};
#pragma unroll
    for (int c = 0; c < 4; c++) {
        const float vs = a_src[h * 128 + ch * 64 + c * 16 + col];
        const float vd = a_dst[h * 128 + ch * 64 + c * 16 + col];
#pragma unroll
        for (int r = 0; r < 4; r++) {
            ssrc[r] += acc[c][r] * vs;
            sdst[r] += acc[c][r] * vd;
        }
    }
#pragma unroll
    for (int mask = 1; mask <= 8; mask <<= 1)
#pragma unroll
        for (int r = 0; r < 4; r++) {
            ssrc[r] += __shfl_xor(ssrc[r], mask);
            sdst[r] += __shfl_xor(sdst[r], mask);
        }
    if (col == 0) {
#pragma unroll
        for (int r = 0; r < 4; r++) {
            const int row = i0 + q4 * 4 + r;
            atomicAdd(asrc + h * CNODES + row, ssrc[r]);   // exactly 2 contributors
            atomicAdd(adst + h * CNODES + row, sdst[r]);
        }
    }
    // wave max of half-dot -> one atomic per block
    float wmax = fmaxf(fmaxf(sdst[0], sdst[1]), fmaxf(sdst[2], sdst[3]));
    wmax = fmaxf(wmax, __shfl_xor(wmax, 16));
    wmax = fmaxf(wmax, __shfl_xor(wmax, 32));
    if (lane == 0) atomicMax(MhEncH + h * 2 + ch, encf(wmax));
}

// ---------------------------------------------------------------------------
// gemm_doc: doc_h tile = relu(A @ B^T + bias) -> bf16 A-frags (dhf).
// n-tile 32 (2 B-frags): grid (BDOCS/16, HID/32) = 1024 blocks.
// ---------------------------------------------------------------------------
template <int KC>
__global__ __launch_bounds__(64)
void gemm_doc(const short* __restrict__ Af, const short* __restrict__ Bf,
              const float* __restrict__ bias, short* __restrict__ dhf)
{
    __shared__ __align__(16) short tile[16][32];
    const int lane = threadIdx.x;
    const int mb = blockIdx.x;
    const int ng = blockIdx.y;    // 32-col group, 0..15

    f32x4 acc[2];
#pragma unroll
    for (int c = 0; c < 2; c++) acc[c] = (f32x4){0.f, 0.f, 0.f, 0.f};

    const short* ap = Af + (size_t)mb * KC * 512 + lane * 8;
    const short* bp = Bf + (size_t)(ng * 2) * KC * 512 + lane * 8;

#pragma unroll 2
    for (int kc = 0; kc < KC; kc++) {
        short8 a = *(const short8*)(ap + (size_t)kc * 512);
#pragma unroll
        for (int c = 0; c < 2; c++) {
            short8 bf = *(const short8*)(bp + ((size_t)c * KC + kc) * 512);
            acc[c] = __builtin_amdgcn_mfma_f32_16x16x32_bf16(a, bf, acc[c], 0, 0, 0);
        }
    }

    const int col = lane & 15, q4 = lane >> 4;
#pragma unroll
    for (int c = 0; c < 2; c++)
#pragma unroll
        for (int r = 0; r < 4; r++) {
            float v = fmaxf(acc[c][r] + bias[ng * 32 + c * 16 + col], 0.f);
            tile[q4 * 4 + r][c * 16 + col] = f2bf(v);
        }
    __syncthreads();
    const int m = lane & 15, kq = lane >> 4;
    short8 v = *(const short8*)&tile[m][kq * 8];
    *(short8*)&dhf[(((size_t)mb * 16 + ng) * 64 + lane) * 8] = v;
}

// ---------------------------------------------------------------------------
// gemm_frag: C[M][N] fp32 = A @ B^T from bf16 fragments (logits).
// m-tile 32, n-tile 64: grid (BDOCS/32, CNODES/64) = 2048 one-wave blocks.
// ---------------------------------------------------------------------------
template <int KC>
__global__ __launch_bounds__(64)
void gemm_frag(const short* __restrict__ Af, const short* __restrict__ Bf,
               float* __restrict__ Cmat, int N)
{
    const int lane = threadIdx.x;
    const int mb0  = blockIdx.x * 2;
    const int ng   = blockIdx.y;    // 64-col group

    f32x4 acc[2][4];
#pragma unroll
    for (int f = 0; f < 2; f++)
#pragma unroll
        for (int c = 0; c < 4; c++) acc[f][c] = (f32x4){0.f, 0.f, 0.f, 0.f};

    const short* ap0 = Af + (size_t)mb0 * KC * 512 + lane * 8;
    const short* ap1 = ap0 + (size_t)KC * 512;
    const short* bp  = Bf + (size_t)(ng * 4) * KC * 512 + lane * 8;

#pragma unroll 2
    for (int kc = 0; kc < KC; kc++) {
        short8 a0 = *(const short8*)(ap0 + (size_t)kc * 512);
        short8 a1 = *(const short8*)(ap1 + (size_t)kc * 512);
#pragma unroll
        for (int c = 0; c < 4; c++) {
            short8 bf = *(const short8*)(bp + ((size_t)c * KC + kc) * 512);
            acc[0][c] = __builtin_amdgcn_mfma_f32_16x16x32_bf16(a0, bf, acc[0][c], 0, 0, 0);
            acc[1][c] = __builtin_amdgcn_mfma_f32_16x16x32_bf16(a1, bf, acc[1][c], 0, 0, 0);
        }
    }

    const int col = lane & 15, q4 = lane >> 4;
#pragma unroll
    for (int f = 0; f < 2; f++)
#pragma unroll
        for (int c = 0; c < 4; c++)
#pragma unroll
            for (int r = 0; r < 4; r++) {
                const int row = (mb0 + f) * 16 + q4 * 4 + r;
                Cmat[(size_t)row * N + ng * 64 + c * 16 + col] = acc[f][c][r];
            }
}

// ---------------------------------------------------------------------------
// attn_pv: partial[ks][i][n] (bf16) = sum_{j in slice} w_ij * V[j][n].
// 512-thread blocks = 8 waves (wave = (i-half, head)), E1/E2 in LDS preamble,
// Mh = sum of half maxima (upper bound; weights exact). grid (64, 8).
// ---------------------------------------------------------------------------
__global__ __launch_bounds__(512, 2)
void attn_pv(const short* __restrict__ hbTf,
             const unsigned int* __restrict__ adjb,
             const float* __restrict__ asrc, const float* __restrict__ adst,
             const unsigned* __restrict__ MhEncH,
             short* __restrict__ part, float* __restrict__ lpart)
{
    __shared__ __align__(16) float E1s[NHEAD][512];    // 8 KB
    __shared__ __align__(16) float E2s[NHEAD][512];    // 8 KB
    __shared__ __align__(16) short tileO[32][520];     // 33.3 KB

    const int t    = threadIdx.x;
    const int ww   = t >> 6;
    const int w    = ww & 3;        // head
    const int f2   = ww >> 2;       // i-half (0/1)
    const int lane = t & 63;
    const int m    = lane & 15;
    const int kq   = lane >> 4;
    const int i0   = blockIdx.x * 64;
    const int iw   = i0 + f2 * 32;
    const int ks   = blockIdx.y;
    const int js   = ks * JPER;

    // ---- preamble: E1/E2 for this slice into LDS (t indexes j) ----
    {
        const int j = js + t;
#pragma unroll
        for (int h = 0; h < NHEAD; h++) {
            const float mhh = decf(MhEncH[h * 2]) + decf(MhEncH[h * 2 + 1]);
            const float d = adst[h * CNODES + j] - mhh;
            E1s[h][t] = __expf(d);
            E2s[h][t] = __expf(0.2f * d);
        }
    }

    const float mh  = decf(MhEncH[w * 2]) + decf(MhEncH[w * 2 + 1]);
    const float as0 = asrc[w * CNODES + iw + m];
    const float as1 = asrc[w * CNODES + iw + 16 + m];
    const float mr0 = lrelu(as0 + mh), mr1 = lrelu(as1 + mh);
    const float A10 = __expf(as0 + mh - mr0),          A11 = __expf(as1 + mh - mr1);
    const float A20 = __expf(0.2f * (as0 + mh) - mr0), A21 = __expf(0.2f * (as1 + mh) - mr1);
    const float T00 = __expf(-as0 - mh),               T01 = __expf(-as1 - mh);

    f32x4 acc[2][8], accO[2];
#pragma unroll
    for (int f = 0; f < 2; f++) {
        accO[f] = (f32x4){0.f, 0.f, 0.f, 0.f};
#pragma unroll
        for (int c = 0; c < 8; c++) acc[f][c] = (f32x4){0.f, 0.f, 0.f, 0.f};
    }
    short8 ones;
#pragma unroll
    for (int q = 0; q < 8; q++) ones[q] = (short)0x3F80;   // bf16 1.0

    const unsigned int* ar0 = adjb + (size_t)(iw + m) * 128 + ks * NCH;
    const unsigned int* ar1 = adjb + (size_t)(iw + 16 + m) * 128 + ks * NCH;

    __syncthreads();   // E LDS ready

#pragma unroll 2
    for (int ch = 0; ch < NCH; ch++) {
        const int jl = ch * 32;
        const unsigned int aw0 = ar0[ch] >> (kq * 8);
        const unsigned int aw1 = ar1[ch] >> (kq * 8);
        const float4 x0 = *(const float4*)&E1s[w][jl + kq * 8];
        const float4 x1 = *(const float4*)&E1s[w][jl + kq * 8 + 4];
        const float4 y0 = *(const float4*)&E2s[w][jl + kq * 8];
        const float4 y1 = *(const float4*)&E2s[w][jl + kq * 8 + 4];
        const float e1v[8] = {x0.x, x0.y, x0.z, x0.w, x1.x, x1.y, x1.z, x1.w};
        const float e2v[8] = {y0.x, y0.y, y0.z, y0.w, y1.x, y1.y, y1.z, y1.w};

        short8 a0, a1;
#pragma unroll
        for (int q = 0; q < 8; q++) {
            const float e1 = e1v[q], e2 = e2v[q];
            const bool c0 = e1 > T00, c1 = e1 > T01;
            float w0 = (c0 ? A10 : A20) * (c0 ? e1 : e2);
            float w1 = (c1 ? A11 : A21) * (c1 ? e1 : e2);
            w0 = ((aw0 >> q) & 1u) ? w0 : 0.f;
            w1 = ((aw1 >> q) & 1u) ? w1 : 0.f;
            a0[q] = hup(w0);
            a1[q] = hup(w1);
        }

        const short* bbase = hbTf + (((size_t)(w * 8) * 128 + ((js + jl) >> 5)) * 64 + lane) * 8;
#pragma unroll
        for (int c = 0; c < 8; c++) {
            short8 bf = *(const short8*)(bbase + (size_t)c * 128 * 64 * 8);
            acc[0][c] = __builtin_amdgcn_mfma_f32_16x16x32_bf16(a0, bf, acc[0][c], 0, 0, 0);
            acc[1][c] = __builtin_amdgcn_mfma_f32_16x16x32_bf16(a1, bf, acc[1][c], 0, 0, 0);
        }
        accO[0] = __builtin_amdgcn_mfma_f32_16x16x32_bf16(a0, ones, accO[0], 0, 0, 0);
        accO[1] = __builtin_amdgcn_mfma_f32_16x16x32_bf16(a1, ones, accO[1], 0, 0, 0);
    }

    if (m == 0) {
#pragma unroll
        for (int f = 0; f < 2; f++)
#pragma unroll
            for (int r = 0; r < 4; r++)
                lpart[((size_t)ks * NHEAD + w) * CNODES + iw + f * 16 + kq * 4 + r] = accO[f][r];
    }

    // bf16 partials via 32-row LDS tile, one round per i-half
    short* pS = part + (size_t)ks * CNODES * HID;
    for (int half = 0; half < 2; half++) {
        __syncthreads();
        if (f2 == half) {
#pragma unroll
            for (int f = 0; f < 2; f++)
#pragma unroll
                for (int c = 0; c < 8; c++)
#pragma unroll
                    for (int r = 0; r < 4; r++)
                        tileO[f * 16 + kq * 4 + r][w * 128 + c * 16 + m] = f2bf(acc[f][c][r]);
        }
        __syncthreads();
#pragma unroll
        for (int it = 0; it < 4; it++) {
            const int u   = it * 512 + t;
            const int row = u >> 6, un = u & 63;
            uint4 v = *(const uint4*)&tileO[row][un * 8];
            *(uint4*)&pS[(size_t)(i0 + half * 32 + row) * HID + un * 8] = v;
        }
    }
}

// ---------------------------------------------------------------------------
// reduce_norm_frag: out = (sum_s part)/(sum_s lpart), optional ELU, written
// directly as bf16 fragments.
// ---------------------------------------------------------------------------
template <bool ELU>
__global__ __launch_bounds__(256)
void reduce_norm_frag(const short* __restrict__ part, const float* __restrict__ lpart,
                      short* __restrict__ dst)
{
    const int t = threadIdx.x;
    const int W = blockIdx.x * 4 + (t >> 6);
    const int lane = t & 63;
    const int rb = W >> 4, kc = W & 15;
    const int m = lane & 15, kq = lane >> 4;
    const int i = rb * 16 + m;
    const int n0 = kc * 32 + kq * 8;
    const int h = kc >> 2;

    float v[8] = {};
    float l = 0.f;
#pragma unroll
    for (int s = 0; s < KSPLIT; s++) {
        const uint4 raw = *(const uint4*)&part[(size_t)s * CNODES * HID + (size_t)i * HID + n0];
        const unsigned rr[4] = {raw.x, raw.y, raw.z, raw.w};
#pragma unroll
        for (int q = 0; q < 4; q++) {
            v[q * 2]     += bf2f((short)(rr[q] & 0xffff));
            v[q * 2 + 1] += bf2f((short)(rr[q] >> 16));
        }
        l += lpart[((size_t)s * NHEAD + h) * CNODES + i];
    }
    const float inv = 1.0f / l;
    short8 o;
#pragma unroll
    for (int q = 0; q < 8; q++) {
        float x = v[q] * inv;
        if (ELU) x = x > 0.f ? x : (__expf(x) - 1.f);
        o[q] = f2bf(x);
    }
    *(short8*)&dst[((size_t)(rb * 16 + kc) * 64 + lane) * 8] = o;
}

// ---------------------------------------------------------------------------
extern "C" void kernel_launch(void* const* d_in, const int* in_sizes, int n_in,
                              void* d_out, int out_size, void* d_ws, size_t ws_size,
                              hipStream_t stream)
{
    const float* doc_x      = (const float*)d_in[0];
    const float* label_init = (const float*)d_in[1];
    const int*   adj        = (const int*)d_in[2];
    const float* W1         = (const float*)d_in[3];
    const float* a_src1     = (const float*)d_in[4];
    const float* a_dst1     = (const float*)d_in[5];
    const float* W2         = (const float*)d_in[6];
    const float* a_src2     = (const float*)d_in[7];
    const float* a_dst2     = (const float*)d_in[8];
    const float* Wd         = (const float*)d_in[9];
    const float* bd         = (const float*)d_in[10];
    float*       out        = (float*)d_out;

    char* wsb = (char*)d_ws;
    size_t off = 0;
    auto alloc = [&](size_t bytes) -> char* {
        char* p = wsb + off;
        off = (off + bytes + 255) & ~(size_t)255;
        return p;
    };

    float* asrc  = (float*)alloc(NHEAD * CNODES * 4);   // zeroed (atomicAdd targets)
    float* adst  = (float*)alloc(NHEAD * CNODES * 4);
    unsigned* MhEncH = (unsigned*)alloc(256);           // 0..7 L1 halves, 8..15 L2
    float* lpart = (float*)alloc((size_t)KSPLIT * NHEAD * CNODES * 4);
    unsigned int* adjb = (unsigned int*)alloc((size_t)CNODES * 128 * 4);   // 2 MB
    short* hbTf  = (short*)alloc((size_t)CNODES * HID * 2);                // 4 MB
    short* Wdf   = (short*)alloc((size_t)INDIM * HID * 2);
    short* W1f   = (short*)alloc((size_t)INDIM * HID * 2);
    short* W2f   = (short*)alloc((size_t)HID * HID * 2);
    short* dxf   = (short*)alloc((size_t)BDOCS * INDIM * 2);
    short* Af_li = (short*)alloc((size_t)CNODES * INDIM * 2);              // 6 MB
    short* Af2   = (short*)alloc((size_t)CNODES * HID * 2);                // 4 MB
    short* lhf   = (short*)alloc((size_t)CNODES * HID * 2);                // 4 MB
    short* dhf   = (short*)alloc((size_t)BDOCS * HID * 2);                 // 1 MB
    short* part  = (short*)alloc((size_t)KSPLIT * CNODES * HID * 2);       // 32 MB
    (void)ws_size;

    const dim3 blk(256);

    // zero the atomicAdd accumulators (asrc+adst contiguous)
    hipMemsetAsync(asrc, 0, (size_t)2 * NHEAD * CNODES * 4, stream);

    // all one-time transforms in a single dispatch (also inits MhEncH)
    prep_all<<<PREP_BLOCKS, blk, 0, stream>>>(adj, (unsigned long long*)adjb,
                                              Wd, Wdf, W1, W1f, W2, W2f,
                                              doc_x, dxf, label_init, Af_li, MhEncH);

    // doc_h = relu(doc_x @ Wd + bd) -> dhf A-frags (fused)
    gemm_doc<INDIM / 32><<<dim3(BDOCS / 16, HID / 32), 64, 0, stream>>>(dxf, Wdf, bd, dhf);

    // hpre1 = label_init @ W1 -> hbTf B-frags + asrc/adst + Mh halves (fused)
    gemm_hpre<INDIM / 32><<<dim3(CNODES / 16, 2 * NHEAD), 64, 0, stream>>>(
        Af_li, W1f, a_src1, a_dst1, hbTf, asrc, adst, MhEncH);

    // GAT layer 1
    attn_pv<<<dim3(CNODES / 64, KSPLIT), 512, 0, stream>>>(
        hbTf, adjb, asrc, adst, MhEncH, part, lpart);
    reduce_norm_frag<true><<<CNODES * HID / 256 / 8, blk, 0, stream>>>(part, lpart, Af2);

    // re-zero accumulators for layer 2 is NOT needed separately: layer 2 uses
    // fresh buffers below (asrc/adst re-used would race with nothing since
    // stream-ordered, but values must start at 0) -> zero again:
    hipMemsetAsync(asrc, 0, (size_t)2 * NHEAD * CNODES * 4, stream);

    // hpre2 = elu(gat1) @ W2 -> hbTf B-frags + asrc/adst + Mh halves (fused)
    gemm_hpre<HID / 32><<<dim3(CNODES / 16, 2 * NHEAD), 64, 0, stream>>>(
        Af2, W2f, a_src2, a_dst2, hbTf, asrc, adst, MhEncH + 8);

    // GAT layer 2
    attn_pv<<<dim3(CNODES / 64, KSPLIT), 512, 0, stream>>>(
        hbTf, adjb, asrc, adst, MhEncH + 8, part, lpart);
    reduce_norm_frag<false><<<CNODES * HID / 256 / 8, blk, 0, stream>>>(part, lpart, lhf);

    // logits = doc_h @ label_h^T -> out
    gemm_frag<HID / 32><<<dim3(BDOCS / 32, CNODES / 64), 64, 0, stream>>>(dhf, lhf, out, CNODES);
}